// Round 9
// baseline (171.374 us; speedup 1.0000x reference)
//
#include <hip/hip_runtime.h>
#include <hip/hip_bf16.h>

#define DD 256
#define RR 32
#define CC 64
#define PB 96
#define NT 1024

typedef __attribute__((ext_vector_type(8))) short short8;
typedef __attribute__((ext_vector_type(4))) float f32x4;

__device__ __forceinline__ short f2bf(float f) {
    return __builtin_bit_cast(short, __float2bfloat16(f));
}
__device__ __forceinline__ float b2f(unsigned short s) {
    union { unsigned u; float f; } v; v.u = ((unsigned)s) << 16;
    return v.f;
}

// [64][256] bf16: 8-elem-block XOR swizzle by (row&7)
__device__ __forceinline__ int hswz(int c, int d) {
    return c * 256 + (d ^ ((c & 7) << 3));
}
// [*][32] bf16: 8-elem-block XOR swizzle by ((row>>1)&3)
__device__ __forceinline__ int nswz(int r, int k) {
    return r * 32 + (k ^ (((r >> 1) & 3) << 3));
}

// ============ prep kernel: bake MFMA B-fragment images + fp32 transposes ============
// Fragment layout (per 16x16x32 MFMA B operand): frag f, lane l, j=0..7 ->
// element B[n = (l&15)][k = (l>>4)*8 + j]; stored at f*512 + l*8 + j shorts.
__global__ __launch_bounds__(1024, 1)
void prep_kernel(const float* __restrict__ ln_g, const float* __restrict__ ln_b,
                 const float* __restrict__ Wd, const float* __restrict__ bd,
                 const float* __restrict__ Wq, const float* __restrict__ Wk,
                 const float* __restrict__ Wv, const float* __restrict__ Wg,
                 const float* __restrict__ Wu,
                 const float* __restrict__ W1, const float* __restrict__ W2,
                 short* __restrict__ wsF1, short* __restrict__ wsF2,
                 short* __restrict__ wsF3, float* __restrict__ wsLN,
                 float* __restrict__ wsW1T, float* __restrict__ wsW2T)
{
    __shared__ float redp[2048];
    const int t = threadIdx.x;
    {   // ln-fold partials over Wd
        const int r = t >> 5, dblk = t & 31;
        float sa = 0.f, sb = 0.f;
        #pragma unroll
        for (int j = 0; j < 8; ++j) {
            const int d = dblk * 8 + j;
            const float wd = Wd[d * RR + r];
            sa += ln_g[d] * wd;
            sb += ln_b[d] * wd;
        }
        redp[r * 32 + dblk]        = sa;
        redp[1024 + r * 32 + dblk] = sb;
    }
    {   // wsF1: S3 B-frags (gamma*Wd)^T.  f = rt*8+step (16 frags)
        const int f = t >> 6, l = t & 63;
        const int rt = f >> 3, step = f & 7;
        const int r = rt * 16 + (l & 15);
        short8 v;
        #pragma unroll
        for (int j = 0; j < 8; ++j) {
            const int d = step * 32 + (l >> 4) * 8 + j;
            v[j] = f2bf(ln_g[d] * Wd[d * RR + r]);
        }
        *(short8*)&wsF1[f * 512 + l * 8] = v;
    }
    if (t < 512) {  // wsF2: QKVG B-frags. f = m*2+half (8 frags)
        const int f = t >> 6, l = t & 63;
        const int m = f >> 1, half = f & 1;
        const float* Wm = (m == 0) ? Wq : (m == 1) ? Wk : (m == 2) ? Wv : Wg;
        const int rout = half * 16 + (l & 15);
        short8 v;
        #pragma unroll
        for (int j = 0; j < 8; ++j) {
            const int rin = (l >> 4) * 8 + j;
            v[j] = f2bf(Wm[rin * RR + rout]);
        }
        *(short8*)&wsF2[f * 512 + l * 8] = v;
    }
    {   // wsF3: Wu B-frags. f = dt (16 frags)
        const int f = t >> 6, l = t & 63;
        const int d = f * 16 + (l & 15);
        short8 v;
        #pragma unroll
        for (int j = 0; j < 8; ++j) {
            const int r = (l >> 4) * 8 + j;
            v[j] = f2bf(Wu[r * DD + d]);
        }
        *(short8*)&wsF3[f * 512 + l * 8] = v;
    }
    #pragma unroll
    for (int rep = 0; rep < 16; ++rep) {   // W1T[j][d] (64x256 fp32)
        const int id = rep * 1024 + t;
        const int j = id >> 8, d = id & 255;
        wsW1T[j * 256 + d] = W1[d * 64 + j];
    }
    #pragma unroll
    for (int rep = 0; rep < 16; ++rep) {   // W2T[d][j] (256x64 fp32)
        const int id = rep * 1024 + t;
        const int d = id >> 6, j = id & 63;
        wsW2T[d * 64 + j] = W2[j * 256 + d];
    }
    __syncthreads();
    if (t < 32) {
        float s = 0.f;
        #pragma unroll
        for (int g = 0; g < 32; ++g) s += redp[t * 32 + g];
        wsLN[t] = s;                       // ln_a
    } else if (t < 64) {
        const int r = t - 32;
        float s = 0.f;
        #pragma unroll
        for (int g = 0; g < 32; ++g) s += redp[1024 + r * 32 + g];
        wsLN[t] = s + bd[r];               // ln_bv
    }
}

// ================= main kernel =================
__global__ __launch_bounds__(NT, 8)
void hydra_kernel(const float* __restrict__ x,
                  const short* __restrict__ wsF1, const short* __restrict__ wsF2,
                  const short* __restrict__ wsF3, const float* __restrict__ wsLN,
                  const float* __restrict__ wsW1T, const float* __restrict__ wsW2T,
                  const float* __restrict__ bg,
                  const float* __restrict__ bu,
                  const float* __restrict__ b1, const float* __restrict__ b2,
                  float* __restrict__ out)
{
    __shared__ short hbf[CC * DD];      // 32 KB h tile bf16 swizzled -> later mixed bf16
    __shared__ short qg[CC * RR];       // 4 KB  Q_n*G bf16 [c][r] linear
    __shared__ short lowbuf[CC * RR];   // 4 KB  hlow -> Abuf (swizzled nswz)
    __shared__ float redA[1024];        // 4 KB  W1 partials [8][64]@0 ; gf [8][32]@512
    __shared__ float redB[2048];        // 8 KB  chanvar -> kv fp32 -> W2 partials
    __shared__ float redC[1024];        // 4 KB  LN partials (P0->P1): [c][8] float2
    __shared__ float mu_s[CC], rstd_s[CC];
    __shared__ float cv_s[DD], gate_s[DD];
    __shared__ float hid_s[64];
    __shared__ float ln_a[RR], ln_bv[RR];

    const int t    = threadIdx.x;
    const int lane = t & 63;
    const int w    = t >> 6;
    const int bp   = blockIdx.x;
    const int b    = bp / PB;
    const int p    = bp - b * PB;
    const size_t rowbase = (size_t)(b * CC) * PB * DD + (size_t)p * DD;

    // ---- P0: load x -> hbf bf16 swizzled; LN partials; ln vectors ----
    #pragma unroll
    for (int i = 0; i < 4; ++i) {
        const int c = w * 4 + i;
        const float4 v = *(const float4*)(x + rowbase + (size_t)c * (PB * DD) + 4 * lane);
        float s1 = v.x + v.y + v.z + v.w;
        float s2 = v.x * v.x + v.y * v.y + v.z * v.z + v.w * v.w;
        s1 += __shfl_xor(s1, 1, 64); s2 += __shfl_xor(s2, 1, 64);
        s1 += __shfl_xor(s1, 2, 64); s2 += __shfl_xor(s2, 2, 64);
        s1 += __shfl_xor(s1, 4, 64); s2 += __shfl_xor(s2, 4, 64);
        if ((lane & 7) == 0)
            *(float2*)&redC[(c * 8 + (lane >> 3)) * 2] = make_float2(s1, s2);
        ushort4 pk;
        pk.x = (unsigned short)f2bf(v.x); pk.y = (unsigned short)f2bf(v.y);
        pk.z = (unsigned short)f2bf(v.z); pk.w = (unsigned short)f2bf(v.w);
        *(ushort4*)&hbf[hswz(c, 4 * lane)] = pk;
    }
    if (t < 32)              ln_a[t]       = wsLN[t];
    else if (t < 64)         ln_bv[t - 32] = wsLN[t];
    __syncthreads();

    // ---- P1: [w0-7] S3 MFMA (h @ gWd), B-frags from L2   [w8-15] chan_var + LN finalize ----
    f32x4 s3acc = {0.f, 0.f, 0.f, 0.f};
    if (w < 8) {
        const int ct = w >> 1, rt = w & 1;
        const int arow = ct * 16 + (lane & 15);
        const int kofs = (lane >> 4) * 8;
        const short* fB = wsF1 + rt * 8 * 512 + lane * 8;
        #pragma unroll
        for (int step = 0; step < 8; ++step) {
            const short8 bf = *(const short8*)(fB + step * 512);
            const short8 a  = *(const short8*)&hbf[hswz(arow, step * 32 + kofs)];
            s3acc = __builtin_amdgcn_mfma_f32_16x16x32_bf16(a, bf, s3acc, 0, 0, 0);
        }
    } else {
        const int idx = t - 512;                 // 0..511
        const int dp  = idx & 127;
        const int rg  = idx >> 7;
        const int d0  = dp * 2;
        float s1a = 0.f, s1b = 0.f, s2a = 0.f, s2b = 0.f;
        #pragma unroll
        for (int i = 0; i < 16; ++i) {
            const int c = rg * 16 + i;
            const ushort2 u = *(const ushort2*)&hbf[hswz(c, d0)];
            const float va = b2f(u.x), vb = b2f(u.y);
            s1a += va; s2a += va * va;
            s1b += vb; s2b += vb * vb;
        }
        *(float2*)&redB[rg * 256 + d0]        = make_float2(s1a, s1b);
        *(float2*)&redB[1024 + rg * 256 + d0] = make_float2(s2a, s2b);
        if (idx < 64) {                          // LN finalize for row c=idx
            const int c = idx;
            float s1 = 0.f, s2 = 0.f;
            #pragma unroll
            for (int g = 0; g < 8; ++g) {
                const float2 pr = *(const float2*)&redC[(c * 8 + g) * 2];
                s1 += pr.x; s2 += pr.y;
            }
            const float mu = s1 * (1.f / 256.f);
            mu_s[c]   = mu;
            rstd_s[c] = rsqrtf(s2 * (1.f / 256.f) - mu * mu + 1e-5f);
        }
    }
    __syncthreads();

    // ---- P2: [w0-7] S3 epilogue -> lowbuf   [w8-11] cv finalize ----
    if (w < 8) {
        const int ct = w >> 1, rt = w & 1;
        const int col = rt * 16 + (lane & 15);
        const float la = ln_a[col], lb = ln_bv[col];
        #pragma unroll
        for (int i = 0; i < 4; ++i) {
            const int c = ct * 16 + (lane >> 4) * 4 + i;
            const float rs = rstd_s[c];
            const float hl = rs * s3acc[i] - rs * mu_s[c] * la + lb;
            lowbuf[nswz(c, col)] = f2bf(hl);
        }
    } else if (t < 768) {
        const int d = t - 512;
        const float S1 = redB[d] + redB[256 + d] + redB[512 + d] + redB[768 + d];
        const float S2 = redB[1024 + d] + redB[1280 + d] + redB[1536 + d] + redB[1792 + d];
        cv_s[d] = (S2 - S1 * S1 * (1.f / 64.f)) * (1.f / 63.f);
    }
    __syncthreads();

    // ---- P3: [w0-7] S5 MFMA (QG / KV), B-frags from L2   [w8-15] W1 partials ----
    if (w < 8) {
        const int ct = w >> 1, pair = w & 1;
        const int mA = pair ? 1 : 0;   // K or Q (l2-normalized)
        const int mB = pair ? 2 : 3;   // V or G
        const int arow = ct * 16 + (lane & 15);
        const int kofs = (lane >> 4) * 8;
        const short8 a = *(const short8*)&lowbuf[nswz(arow, kofs)];
        const short8 bA0 = *(const short8*)(wsF2 + (mA * 2 + 0) * 512 + lane * 8);
        const short8 bA1 = *(const short8*)(wsF2 + (mA * 2 + 1) * 512 + lane * 8);
        const short8 bB0 = *(const short8*)(wsF2 + (mB * 2 + 0) * 512 + lane * 8);
        const short8 bB1 = *(const short8*)(wsF2 + (mB * 2 + 1) * 512 + lane * 8);
        f32x4 aA0 = {0,0,0,0}, aA1 = {0,0,0,0}, aB0 = {0,0,0,0}, aB1 = {0,0,0,0};
        aA0 = __builtin_amdgcn_mfma_f32_16x16x32_bf16(a, bA0, aA0, 0, 0, 0);
        aA1 = __builtin_amdgcn_mfma_f32_16x16x32_bf16(a, bA1, aA1, 0, 0, 0);
        aB0 = __builtin_amdgcn_mfma_f32_16x16x32_bf16(a, bB0, aB0, 0, 0, 0);
        aB1 = __builtin_amdgcn_mfma_f32_16x16x32_bf16(a, bB1, aB1, 0, 0, 0);
        float qs[4];
        #pragma unroll
        for (int i = 0; i < 4; ++i) {
            float ss = aA0[i] * aA0[i] + aA1[i] * aA1[i];
            ss += __shfl_xor(ss, 1, 64);
            ss += __shfl_xor(ss, 2, 64);
            ss += __shfl_xor(ss, 4, 64);
            ss += __shfl_xor(ss, 8, 64);
            qs[i] = 1.f / fmaxf(sqrtf(ss), 1e-12f);
        }
        const int col0 = (lane & 15), col1 = 16 + (lane & 15);
        if (pair == 0) {
            const float bgv0 = bg[col0], bgv1 = bg[col1];
            #pragma unroll
            for (int i = 0; i < 4; ++i) {
                const int c = ct * 16 + (lane >> 4) * 4 + i;
                const float g0 = 1.f / (1.f + __expf(-(aB0[i] + bgv0)));
                const float g1 = 1.f / (1.f + __expf(-(aB1[i] + bgv1)));
                qg[c * 32 + col0] = f2bf(aA0[i] * qs[i] * g0);
                qg[c * 32 + col1] = f2bf(aA1[i] * qs[i] * g1);
            }
        } else {
            #pragma unroll
            for (int i = 0; i < 4; ++i) {
                const int c = ct * 16 + (lane >> 4) * 4 + i;
                redB[c * 32 + col0] = aA0[i] * qs[i] * aB0[i];   // K_n * V, fp32
                redB[c * 32 + col1] = aA1[i] * qs[i] * aB1[i];
            }
        }
    } else {
        const int idx = t - 512;
        const int j = idx & 63, dg = idx >> 6;   // 8 d-groups of 32
        const float* w1row = wsW1T + j * 256 + dg * 32;
        float s = 0.f;
        #pragma unroll
        for (int ii = 0; ii < 8; ++ii) {
            const float4 wv = *(const float4*)(w1row + ii * 4);
            const float4 cvv = *(const float4*)&cv_s[dg * 32 + ii * 4];
            s += cvv.x * wv.x + cvv.y * wv.y + cvv.z * wv.z + cvv.w * wv.w;
        }
        redA[dg * 64 + j] = s;
    }
    __syncthreads();

    // ---- P4: hid gelu ; gf partials ----
    if (t < 64) {
        float s = b1[t];
        #pragma unroll
        for (int g = 0; g < 8; ++g) s += redA[g * 64 + t];
        hid_s[t] = 0.5f * s * (1.f + erff(s * 0.70710678118654752f));
    }
    if (t >= 256 && t < 512) {
        const int idx = t - 256;
        const int r = idx & 31, g = idx >> 5;
        float s = 0.f;
        #pragma unroll
        for (int i = 0; i < 8; ++i)
            s += redB[(g * 8 + i) * 32 + r];
        redA[512 + g * 32 + r] = s;
    }
    __syncthreads();

    // ---- P5: W2 partials ; Abuf = qg * gf -> lowbuf ----
    {
        const int d = t & 255, jg = t >> 8;
        const float* w2row = wsW2T + d * 64 + jg * 16;
        float s = 0.f;
        #pragma unroll
        for (int ii = 0; ii < 4; ++ii) {
            const float4 wv = *(const float4*)(w2row + ii * 4);
            const float4 hv = *(const float4*)&hid_s[jg * 16 + ii * 4];
            s += hv.x * wv.x + hv.y * wv.y + hv.z * wv.z + hv.w * wv.w;
        }
        redB[jg * 256 + d] = s;
    }
    if (t < 256) {
        const int r = t & 31, c0 = t >> 5, c1 = (t >> 5) + 32;
        float gf = 0.f;
        #pragma unroll
        for (int g = 0; g < 8; ++g) gf += redA[512 + g * 32 + r];
        lowbuf[nswz(c0, r)] = f2bf(b2f((unsigned short)qg[c0 * 32 + r]) * gf);
        lowbuf[nswz(c1, r)] = f2bf(b2f((unsigned short)qg[c1 * 32 + r]) * gf);
    }
    __syncthreads();

    // ---- P6: S8 MFMA (Abuf @ Wu), B-frags from L2 -> mixed bf16 into hbf ; gate finalize ----
    {
        const int ct = w & 3, dg = w >> 2;
        const int arow = ct * 16 + (lane & 15);
        const int kofs = (lane >> 4) * 8;
        const short8 a = *(const short8*)&lowbuf[nswz(arow, kofs)];
        #pragma unroll
        for (int j = 0; j < 4; ++j) {
            const int dt = dg * 4 + j;
            const int col = dt * 16 + (lane & 15);
            const short8 bf = *(const short8*)(wsF3 + dt * 512 + lane * 8);
            f32x4 acc = {0.f, 0.f, 0.f, 0.f};
            acc = __builtin_amdgcn_mfma_f32_16x16x32_bf16(a, bf, acc, 0, 0, 0);
            #pragma unroll
            for (int i = 0; i < 4; ++i) {
                const int c = ct * 16 + (lane >> 4) * 4 + i;
                hbf[hswz(c, col)] = f2bf(acc[i]);
            }
        }
    }
    if (t < 256) {
        const float s = redB[t] + redB[256 + t] + redB[512 + t] + redB[768 + t] + b2[t];
        gate_s[t] = 1.f / (1.f + __expf(-s));
    }
    __syncthreads();

    // ---- P7: coalesced residual sweep: out = x + gate*(mixed + bu) ----
    #pragma unroll
    for (int i = 0; i < 4; ++i) {
        const int c = w * 4 + i;
        const size_t off = rowbase + (size_t)c * (PB * DD) + 4 * lane;
        const float4 xv = *(const float4*)(x + off);
        const ushort4 m = *(const ushort4*)&hbf[hswz(c, 4 * lane)];
        const float4 g4 = *(const float4*)&gate_s[4 * lane];
        const float4 bu4 = *(const float4*)(bu + 4 * lane);
        float4 o;
        o.x = xv.x + g4.x * (b2f(m.x) + bu4.x);
        o.y = xv.y + g4.y * (b2f(m.y) + bu4.y);
        o.z = xv.z + g4.z * (b2f(m.z) + bu4.z);
        o.w = xv.w + g4.w * (b2f(m.w) + bu4.w);
        *(float4*)(out + off) = o;
    }
}

extern "C" void kernel_launch(void* const* d_in, const int* in_sizes, int n_in,
                              void* d_out, int out_size, void* d_ws, size_t ws_size,
                              hipStream_t stream) {
    (void)in_sizes; (void)n_in; (void)out_size; (void)ws_size;
    const float* x    = (const float*)d_in[0];
    const float* ln_g = (const float*)d_in[1];
    const float* ln_b = (const float*)d_in[2];
    const float* Wd   = (const float*)d_in[3];
    const float* bd   = (const float*)d_in[4];
    const float* Wq   = (const float*)d_in[5];
    const float* Wk   = (const float*)d_in[6];
    const float* Wv   = (const float*)d_in[7];
    const float* Wg   = (const float*)d_in[8];
    const float* bg   = (const float*)d_in[9];
    const float* Wu   = (const float*)d_in[10];
    const float* bu   = (const float*)d_in[11];
    const float* W1   = (const float*)d_in[12];
    const float* b1   = (const float*)d_in[13];
    const float* W2   = (const float*)d_in[14];
    const float* b2   = (const float*)d_in[15];
    float* out = (float*)d_out;

    short* wsF1  = (short*)d_ws;                   // 8192 shorts @ 0
    short* wsF2  = wsF1 + 8192;                    // 4096 shorts @ 16384B
    short* wsF3  = wsF2 + 4096;                    // 8192 shorts @ 24576B
    float* wsLN  = (float*)(wsF1 + 20480);         // 64 floats   @ 40960B
    float* wsW1T = wsLN + 64;                      // 16384 f     @ 41216B
    float* wsW2T = wsW1T + 16384;                  // 16384 f     @ 106752B

    prep_kernel<<<dim3(1), dim3(1024), 0, stream>>>(
        ln_g, ln_b, Wd, bd, Wq, Wk, Wv, Wg, Wu, W1, W2,
        wsF1, wsF2, wsF3, wsLN, wsW1T, wsW2T);
    hydra_kernel<<<dim3(32 * PB), dim3(NT), 0, stream>>>(
        x, wsF1, wsF2, wsF3, wsLN, wsW1T, wsW2T, bg, bu, b1, b2, out);
}

// Round 10
// 165.466 us; speedup vs baseline: 1.0357x; 1.0357x over previous
//
#include <hip/hip_runtime.h>
#include <hip/hip_bf16.h>

#define DD 256
#define RR 32
#define CC 64
#define PB 96
#define NT 512

typedef __attribute__((ext_vector_type(8))) short short8;
typedef __attribute__((ext_vector_type(4))) float f32x4;

__device__ __forceinline__ short f2bf(float f) {
    return __builtin_bit_cast(short, __float2bfloat16(f));
}
__device__ __forceinline__ float b2f(unsigned short s) {
    union { unsigned u; float f; } v; v.u = ((unsigned)s) << 16;
    return v.f;
}

// [64][256] bf16: 8-elem-block XOR swizzle by (row&7)
__device__ __forceinline__ int hswz(int c, int d) {
    return c * 256 + (d ^ ((c & 7) << 3));
}
// [*][32] bf16: 8-elem-block XOR swizzle by ((row>>1)&3)
__device__ __forceinline__ int nswz(int r, int k) {
    return r * 32 + (k ^ (((r >> 1) & 3) << 3));
}

// ============ prep kernel: bake MFMA B-fragment images ============
// frag f, lane l, j -> B[n=(l&15)][k=(l>>4)*8+j] at f*512 + l*8 + j shorts.
__global__ __launch_bounds__(1024, 1)
void prep_kernel(const float* __restrict__ ln_g, const float* __restrict__ ln_b,
                 const float* __restrict__ Wd, const float* __restrict__ bd,
                 const float* __restrict__ Wq, const float* __restrict__ Wk,
                 const float* __restrict__ Wv, const float* __restrict__ Wg,
                 const float* __restrict__ Wu,
                 short* __restrict__ wsF1, short* __restrict__ wsF2,
                 short* __restrict__ wsF3, float* __restrict__ wsLN)
{
    __shared__ float redp[2048];
    const int t = threadIdx.x;
    {   // ln-fold partials over Wd
        const int r = t >> 5, dblk = t & 31;
        float sa = 0.f, sb = 0.f;
        #pragma unroll
        for (int j = 0; j < 8; ++j) {
            const int d = dblk * 8 + j;
            const float wd = Wd[d * RR + r];
            sa += ln_g[d] * wd;
            sb += ln_b[d] * wd;
        }
        redp[r * 32 + dblk]        = sa;
        redp[1024 + r * 32 + dblk] = sb;
    }
    {   // wsF1: S3 B-frags (gamma*Wd)^T.  f = rt*8+step (16 frags)
        const int f = t >> 6, l = t & 63;
        const int rt = f >> 3, step = f & 7;
        const int r = rt * 16 + (l & 15);
        short8 v;
        #pragma unroll
        for (int j = 0; j < 8; ++j) {
            const int d = step * 32 + (l >> 4) * 8 + j;
            v[j] = f2bf(ln_g[d] * Wd[d * RR + r]);
        }
        *(short8*)&wsF1[f * 512 + l * 8] = v;
    }
    if (t < 512) {  // wsF2: QKVG B-frags. f = m*2+half
        const int f = t >> 6, l = t & 63;
        const int m = f >> 1, half = f & 1;
        const float* Wm = (m == 0) ? Wq : (m == 1) ? Wk : (m == 2) ? Wv : Wg;
        const int rout = half * 16 + (l & 15);
        short8 v;
        #pragma unroll
        for (int j = 0; j < 8; ++j) {
            const int rin = (l >> 4) * 8 + j;
            v[j] = f2bf(Wm[rin * RR + rout]);
        }
        *(short8*)&wsF2[f * 512 + l * 8] = v;
    }
    {   // wsF3: Wu B-frags. f = dt (16 frags)
        const int f = t >> 6, l = t & 63;
        const int d = f * 16 + (l & 15);
        short8 v;
        #pragma unroll
        for (int j = 0; j < 8; ++j) {
            const int r = (l >> 4) * 8 + j;
            v[j] = f2bf(Wu[r * DD + d]);
        }
        *(short8*)&wsF3[f * 512 + l * 8] = v;
    }
    __syncthreads();
    if (t < 32) {
        float s = 0.f;
        #pragma unroll
        for (int g = 0; g < 32; ++g) s += redp[t * 32 + g];
        wsLN[t] = s;                       // ln_a
    } else if (t < 64) {
        const int r = t - 32;
        float s = 0.f;
        #pragma unroll
        for (int g = 0; g < 32; ++g) s += redp[1024 + r * 32 + g];
        wsLN[t] = s + bd[r];               // ln_bv
    }
}

// ================= main kernel: 512 threads, 5 barriers =================
__global__ __launch_bounds__(NT, 6)
void hydra_kernel(const float* __restrict__ x,
                  const short* __restrict__ wsF1, const short* __restrict__ wsF2,
                  const short* __restrict__ wsF3, const float* __restrict__ wsLN,
                  const float* __restrict__ bg, const float* __restrict__ bu,
                  const float* __restrict__ W1, const float* __restrict__ b1,
                  const float* __restrict__ W2, const float* __restrict__ b2,
                  float* __restrict__ out)
{
    __shared__ short hbf[CC * DD];   // 32 KB: h (P0-P1); qg@[0,2048) hlow@[2048,4096) (P2-P3); mixed (P4-P5)
    __shared__ float pool_f[1024];   // 4 KB: redC LN partials [64][4][2] (P0-P1) -> Abuf shorts (P3-P4)
    __shared__ float redA[128];      // 512B: gf partials [4][32]
    __shared__ float cv_s[DD];       // 1 KB
    __shared__ float gate_s[DD];     // 1 KB
    __shared__ float mu_s[CC], rstd_s[CC];   // 512B
    __shared__ float hid_s[64];      // 256B
    __shared__ float ln_a[RR], ln_bv[RR];    // 256B

    short* qg   = hbf;               // [64][32] linear, rows 0-7 region of h (dead after P1)
    short* hlow = hbf + 2048;        // nswz [64][32], rows 8-15 region of h (dead after P1)
    short* Abuf = (short*)pool_f;    // nswz [64][32], overlays redC (dead after P1)

    const int t    = threadIdx.x;
    const int lane = t & 63;
    const int w    = t >> 6;         // 0..7
    const int bp   = blockIdx.x;
    const int b    = bp / PB;
    const int p    = bp - b * PB;
    const size_t rowbase = (size_t)(b * CC) * PB * DD + (size_t)p * DD;

    // ---- P0: load x -> hbf bf16 swizzled; LN partials (4-stage shfl); ln vectors ----
    #pragma unroll
    for (int i = 0; i < 8; ++i) {
        const int c = w * 8 + i;
        const float4 v = *(const float4*)(x + rowbase + (size_t)c * (PB * DD) + 4 * lane);
        float s1 = v.x + v.y + v.z + v.w;
        float s2 = v.x * v.x + v.y * v.y + v.z * v.z + v.w * v.w;
        s1 += __shfl_xor(s1, 1, 64); s2 += __shfl_xor(s2, 1, 64);
        s1 += __shfl_xor(s1, 2, 64); s2 += __shfl_xor(s2, 2, 64);
        s1 += __shfl_xor(s1, 4, 64); s2 += __shfl_xor(s2, 4, 64);
        s1 += __shfl_xor(s1, 8, 64); s2 += __shfl_xor(s2, 8, 64);
        if ((lane & 15) == 0)
            *(float2*)&pool_f[(c * 4 + (lane >> 4)) * 2] = make_float2(s1, s2);
        ushort4 pk;
        pk.x = (unsigned short)f2bf(v.x); pk.y = (unsigned short)f2bf(v.y);
        pk.z = (unsigned short)f2bf(v.z); pk.w = (unsigned short)f2bf(v.w);
        *(ushort4*)&hbf[hswz(c, 4 * lane)] = pk;
    }
    if (t < 32)            ln_a[t]       = wsLN[t];
    else if (t < 64)       ln_bv[t - 32] = wsLN[t];
    __syncthreads();

    // ---- P1: [w0-3] LN finalize (own rows) + S3 MFMA x16   [w4-7] chan_var ----
    f32x4 acc0 = {0.f,0.f,0.f,0.f}, acc1 = {0.f,0.f,0.f,0.f};
    if (w < 4) {
        const int ct = w;
        if (lane < 16) {   // LN finalize rows ct*16+lane
            const int c = ct * 16 + lane;
            const float2 p0 = *(const float2*)&pool_f[(c * 4 + 0) * 2];
            const float2 p1 = *(const float2*)&pool_f[(c * 4 + 1) * 2];
            const float2 p2 = *(const float2*)&pool_f[(c * 4 + 2) * 2];
            const float2 p3 = *(const float2*)&pool_f[(c * 4 + 3) * 2];
            const float s1 = p0.x + p1.x + p2.x + p3.x;
            const float s2 = p0.y + p1.y + p2.y + p3.y;
            const float mu = s1 * (1.f / 256.f);
            mu_s[c]   = mu;
            rstd_s[c] = rsqrtf(s2 * (1.f / 256.f) - mu * mu + 1e-5f);
        }
        const int arow = ct * 16 + (lane & 15);
        const int kofs = (lane >> 4) * 8;
        #pragma unroll
        for (int step = 0; step < 8; ++step) {
            const short8 a   = *(const short8*)&hbf[hswz(arow, step * 32 + kofs)];
            const short8 bf0 = *(const short8*)(wsF1 + step * 512 + lane * 8);
            const short8 bf1 = *(const short8*)(wsF1 + (8 + step) * 512 + lane * 8);
            acc0 = __builtin_amdgcn_mfma_f32_16x16x32_bf16(a, bf0, acc0, 0, 0, 0);
            acc1 = __builtin_amdgcn_mfma_f32_16x16x32_bf16(a, bf1, acc1, 0, 0, 0);
        }
    } else {
        const int d = t - 256;   // 0..255
        float s1 = 0.f, s2 = 0.f;
        #pragma unroll 8
        for (int c = 0; c < CC; ++c) {
            const float v = b2f((unsigned short)hbf[hswz(c, d)]);
            s1 += v; s2 += v * v;
        }
        cv_s[d] = (s2 - s1 * s1 * (1.f / 64.f)) * (1.f / 63.f);
    }
    __syncthreads();

    // ---- P2: [w0-3] hlow epilogue (wave-local) + QKVG MFMA x8 + qg/gf   [w4-7] W1 + hid ----
    if (w < 4) {
        const int ct = w;
        const int col0 = lane & 15, col1 = 16 + col0;
        {   // epilogue -> hlow
            const float la0 = ln_a[col0], lb0 = ln_bv[col0];
            const float la1 = ln_a[col1], lb1 = ln_bv[col1];
            #pragma unroll
            for (int i = 0; i < 4; ++i) {
                const int c = ct * 16 + (lane >> 4) * 4 + i;
                const float rs = rstd_s[c], mu = mu_s[c];
                hlow[nswz(c, col0)] = f2bf(rs * acc0[i] - rs * mu * la0 + lb0);
                hlow[nswz(c, col1)] = f2bf(rs * acc1[i] - rs * mu * la1 + lb1);
            }
        }
        const int arow = ct * 16 + col0;
        const int kofs = (lane >> 4) * 8;
        const short8 a = *(const short8*)&hlow[nswz(arow, kofs)];
        const short8 bQ0 = *(const short8*)(wsF2 + 0 * 512 + lane * 8);
        const short8 bQ1 = *(const short8*)(wsF2 + 1 * 512 + lane * 8);
        const short8 bK0 = *(const short8*)(wsF2 + 2 * 512 + lane * 8);
        const short8 bK1 = *(const short8*)(wsF2 + 3 * 512 + lane * 8);
        const short8 bV0 = *(const short8*)(wsF2 + 4 * 512 + lane * 8);
        const short8 bV1 = *(const short8*)(wsF2 + 5 * 512 + lane * 8);
        const short8 bG0 = *(const short8*)(wsF2 + 6 * 512 + lane * 8);
        const short8 bG1 = *(const short8*)(wsF2 + 7 * 512 + lane * 8);
        f32x4 aQ0={0,0,0,0}, aQ1={0,0,0,0}, aK0={0,0,0,0}, aK1={0,0,0,0};
        f32x4 aV0={0,0,0,0}, aV1={0,0,0,0}, aG0={0,0,0,0}, aG1={0,0,0,0};
        aQ0 = __builtin_amdgcn_mfma_f32_16x16x32_bf16(a, bQ0, aQ0, 0, 0, 0);
        aQ1 = __builtin_amdgcn_mfma_f32_16x16x32_bf16(a, bQ1, aQ1, 0, 0, 0);
        aK0 = __builtin_amdgcn_mfma_f32_16x16x32_bf16(a, bK0, aK0, 0, 0, 0);
        aK1 = __builtin_amdgcn_mfma_f32_16x16x32_bf16(a, bK1, aK1, 0, 0, 0);
        aV0 = __builtin_amdgcn_mfma_f32_16x16x32_bf16(a, bV0, aV0, 0, 0, 0);
        aV1 = __builtin_amdgcn_mfma_f32_16x16x32_bf16(a, bV1, aV1, 0, 0, 0);
        aG0 = __builtin_amdgcn_mfma_f32_16x16x32_bf16(a, bG0, aG0, 0, 0, 0);
        aG1 = __builtin_amdgcn_mfma_f32_16x16x32_bf16(a, bG1, aG1, 0, 0, 0);
        float qs[4], ks[4];
        #pragma unroll
        for (int i = 0; i < 4; ++i) {
            float sq = aQ0[i] * aQ0[i] + aQ1[i] * aQ1[i];
            float sk = aK0[i] * aK0[i] + aK1[i] * aK1[i];
            sq += __shfl_xor(sq, 1, 64); sk += __shfl_xor(sk, 1, 64);
            sq += __shfl_xor(sq, 2, 64); sk += __shfl_xor(sk, 2, 64);
            sq += __shfl_xor(sq, 4, 64); sk += __shfl_xor(sk, 4, 64);
            sq += __shfl_xor(sq, 8, 64); sk += __shfl_xor(sk, 8, 64);
            qs[i] = 1.f / fmaxf(sqrtf(sq), 1e-12f);
            ks[i] = 1.f / fmaxf(sqrtf(sk), 1e-12f);
        }
        const float bgv0 = bg[col0], bgv1 = bg[col1];
        float p0 = 0.f, p1 = 0.f;
        #pragma unroll
        for (int i = 0; i < 4; ++i) {
            const int c = ct * 16 + (lane >> 4) * 4 + i;
            const float g0 = 1.f / (1.f + __expf(-(aG0[i] + bgv0)));
            const float g1 = 1.f / (1.f + __expf(-(aG1[i] + bgv1)));
            qg[c * 32 + col0] = f2bf(aQ0[i] * qs[i] * g0);
            qg[c * 32 + col1] = f2bf(aQ1[i] * qs[i] * g1);
            p0 += (aK0[i] * ks[i]) * aV0[i];
            p1 += (aK1[i] * ks[i]) * aV1[i];
        }
        p0 += __shfl_xor(p0, 16, 64); p1 += __shfl_xor(p1, 16, 64);
        p0 += __shfl_xor(p0, 32, 64); p1 += __shfl_xor(p1, 32, 64);
        if (lane < 16) {
            redA[ct * 32 + lane]      = p0;
            redA[ct * 32 + 16 + lane] = p1;
        }
    } else {
        // W1 partials: j = (w-4)*16 + (lane>>2), quarter q = lane&3; in-wave combine -> hid
        const int j = (w - 4) * 16 + (lane >> 2);
        const int q = lane & 3;
        float s = 0.f;
        #pragma unroll 8
        for (int i = 0; i < 64; ++i) {
            const int d = q * 64 + i;
            s += cv_s[d] * W1[d * 64 + j];
        }
        s += __shfl_xor(s, 1, 64);
        s += __shfl_xor(s, 2, 64);
        if (q == 0) {
            const float z = s + b1[j];
            hid_s[j] = 0.5f * z * (1.f + erff(z * 0.70710678118654752f));
        }
    }
    __syncthreads();

    // ---- P3: [t<256] Abuf = qg*gf   [t>=256] gate_s = sigmoid(hid@W2 + b2) ----
    if (t < 256) {
        const int r = t & 31, cb = t >> 5;
        const float gf = redA[r] + redA[32 + r] + redA[64 + r] + redA[96 + r];
        #pragma unroll
        for (int k = 0; k < 8; ++k) {
            const int c = cb * 8 + k;
            Abuf[nswz(c, r)] = f2bf(b2f((unsigned short)qg[c * 32 + r]) * gf);
        }
    } else {
        const int d = t - 256;
        float s = b2[d];
        #pragma unroll 8
        for (int j = 0; j < 64; ++j)
            s += hid_s[j] * W2[j * DD + d];
        gate_s[d] = 1.f / (1.f + __expf(-s));
    }
    __syncthreads();

    // ---- P4: S8 MFMA (Abuf @ Wu frags) -> mixed bf16 into hbf ----
    {
        const int ct = w & 3, dgh = w >> 2;
        const int arow = ct * 16 + (lane & 15);
        const int kofs = (lane >> 4) * 8;
        const short8 a = *(const short8*)&Abuf[nswz(arow, kofs)];
        #pragma unroll
        for (int j = 0; j < 8; ++j) {
            const int dt = dgh * 8 + j;
            const int col = dt * 16 + (lane & 15);
            const short8 bf = *(const short8*)(wsF3 + dt * 512 + lane * 8);
            f32x4 acc = {0.f, 0.f, 0.f, 0.f};
            acc = __builtin_amdgcn_mfma_f32_16x16x32_bf16(a, bf, acc, 0, 0, 0);
            #pragma unroll
            for (int i = 0; i < 4; ++i) {
                const int c = ct * 16 + (lane >> 4) * 4 + i;
                hbf[hswz(c, col)] = f2bf(acc[i]);
            }
        }
    }
    __syncthreads();

    // ---- P5: coalesced residual sweep: out = x + gate*(mixed + bu) ----
    #pragma unroll
    for (int i = 0; i < 8; ++i) {
        const int c = w * 8 + i;
        const size_t off = rowbase + (size_t)c * (PB * DD) + 4 * lane;
        const float4 xv = *(const float4*)(x + off);
        const ushort4 m = *(const ushort4*)&hbf[hswz(c, 4 * lane)];
        const float4 g4 = *(const float4*)&gate_s[4 * lane];
        const float4 bu4 = *(const float4*)(bu + 4 * lane);
        float4 o;
        o.x = xv.x + g4.x * (b2f(m.x) + bu4.x);
        o.y = xv.y + g4.y * (b2f(m.y) + bu4.y);
        o.z = xv.z + g4.z * (b2f(m.z) + bu4.z);
        o.w = xv.w + g4.w * (b2f(m.w) + bu4.w);
        *(float4*)(out + off) = o;
    }
}

extern "C" void kernel_launch(void* const* d_in, const int* in_sizes, int n_in,
                              void* d_out, int out_size, void* d_ws, size_t ws_size,
                              hipStream_t stream) {
    (void)in_sizes; (void)n_in; (void)out_size; (void)ws_size;
    const float* x    = (const float*)d_in[0];
    const float* ln_g = (const float*)d_in[1];
    const float* ln_b = (const float*)d_in[2];
    const float* Wd   = (const float*)d_in[3];
    const float* bd   = (const float*)d_in[4];
    const float* Wq   = (const float*)d_in[5];
    const float* Wk   = (const float*)d_in[6];
    const float* Wv   = (const float*)d_in[7];
    const float* Wg   = (const float*)d_in[8];
    const float* bg   = (const float*)d_in[9];
    const float* Wu   = (const float*)d_in[10];
    const float* bu   = (const float*)d_in[11];
    const float* W1   = (const float*)d_in[12];
    const float* b1   = (const float*)d_in[13];
    const float* W2   = (const float*)d_in[14];
    const float* b2   = (const float*)d_in[15];
    float* out = (float*)d_out;

    short* wsF1 = (short*)d_ws;            // 8192 shorts @ 0
    short* wsF2 = wsF1 + 8192;             // 4096 shorts @ 16384B
    short* wsF3 = wsF2 + 4096;             // 8192 shorts @ 24576B
    float* wsLN = (float*)(wsF1 + 20480);  // 64 floats   @ 40960B

    prep_kernel<<<dim3(1), dim3(1024), 0, stream>>>(
        ln_g, ln_b, Wd, bd, Wq, Wk, Wv, Wg, Wu, wsF1, wsF2, wsF3, wsLN);
    hydra_kernel<<<dim3(32 * PB), dim3(NT), 0, stream>>>(
        x, wsF1, wsF2, wsF3, wsLN, bg, bu, W1, b1, W2, b2, out);
}

// Round 12
// 163.110 us; speedup vs baseline: 1.0507x; 1.0144x over previous
//
#include <hip/hip_runtime.h>
#include <hip/hip_bf16.h>

#define DD 256
#define RR 32
#define CC 64
#define PB 96
#define NT 1024

typedef __attribute__((ext_vector_type(8))) short short8;
typedef __attribute__((ext_vector_type(4))) float f32x4;

__device__ __forceinline__ short f2bf(float f) {
    return __builtin_bit_cast(short, __float2bfloat16(f));
}
__device__ __forceinline__ float b2f(unsigned short s) {
    union { unsigned u; float f; } v; v.u = ((unsigned)s) << 16;
    return v.f;
}

// [64][256] bf16: 8-elem-block XOR swizzle by (row&7)
__device__ __forceinline__ int hswz(int c, int d) {
    return c * 256 + (d ^ ((c & 7) << 3));
}
// [*][32] bf16: 8-elem-block XOR swizzle by ((row>>1)&3)
__device__ __forceinline__ int nswz(int r, int k) {
    return r * 32 + (k ^ (((r >> 1) & 3) << 3));
}

// ================= prep kernel: pre-swizzled bf16 weight images + fp32 transposes =================
__global__ __launch_bounds__(1024, 1)
void prep_kernel(const float* __restrict__ ln_g, const float* __restrict__ ln_b,
                 const float* __restrict__ Wd, const float* __restrict__ bd,
                 const float* __restrict__ Wq, const float* __restrict__ Wk,
                 const float* __restrict__ Wv, const float* __restrict__ Wg,
                 const float* __restrict__ Wu,
                 const float* __restrict__ W1, const float* __restrict__ W2,
                 short* __restrict__ wsWd, short* __restrict__ wsQKVG,
                 short* __restrict__ wsWu, float* __restrict__ wsLN,
                 float* __restrict__ wsW1T, float* __restrict__ wsW2T)
{
    __shared__ float redp[2048];
    const int t = threadIdx.x;
    {   // gWd^T image
        const int r = t >> 5, dblk = t & 31;
        short8 vv;
        float sa = 0.f, sb = 0.f;
        #pragma unroll
        for (int j = 0; j < 8; ++j) {
            const int d = dblk * 8 + j;
            const float wd = Wd[d * RR + r];
            const float g  = ln_g[d];
            vv[j] = f2bf(g * wd);
            sa += g * wd;
            sb += ln_b[d] * wd;
        }
        *(short8*)&wsWd[r * 256 + ((dblk ^ (r & 7)) << 3)] = vv;
        redp[r * 32 + dblk]        = sa;
        redp[1024 + r * 32 + dblk] = sb;
    }
    if (t < 512) {  // Wqkvg^T images
        const int m = t >> 7, rr2 = (t >> 2) & 31, kg = t & 3;
        const float* Wm = (m == 0) ? Wq : (m == 1) ? Wk : (m == 2) ? Wv : Wg;
        short8 vv;
        #pragma unroll
        for (int j = 0; j < 8; ++j)
            vv[j] = f2bf(Wm[(kg * 8 + j) * RR + rr2]);
        *(short8*)&wsQKVG[m * 1024 + rr2 * 32 + ((kg ^ ((rr2 >> 1) & 3)) << 3)] = vv;
    }
    {   // Wu^T image
        const int d = t & 255, kg = t >> 8;
        short8 vv;
        #pragma unroll
        for (int j = 0; j < 8; ++j)
            vv[j] = f2bf(Wu[(kg * 8 + j) * DD + d]);
        *(short8*)&wsWu[d * 32 + ((kg ^ ((d >> 1) & 3)) << 3)] = vv;
    }
    #pragma unroll
    for (int rep = 0; rep < 16; ++rep) {   // W1T[j][d] (64x256 fp32)
        const int id = rep * 1024 + t;
        const int j = id >> 8, d = id & 255;
        wsW1T[j * 256 + d] = W1[d * 64 + j];
    }
    #pragma unroll
    for (int rep = 0; rep < 16; ++rep) {   // W2T[d][j] (256x64 fp32)
        const int id = rep * 1024 + t;
        const int d = id >> 6, j = id & 63;
        wsW2T[d * 64 + j] = W2[j * 256 + d];
    }
    __syncthreads();
    if (t < 32) {
        float s = 0.f;
        #pragma unroll
        for (int g = 0; g < 32; ++g) s += redp[t * 32 + g];
        wsLN[t] = s;                       // ln_a
    } else if (t < 64) {
        const int r = t - 32;
        float s = 0.f;
        #pragma unroll
        for (int g = 0; g < 32; ++g) s += redp[1024 + r * 32 + g];
        wsLN[t] = s + bd[r];               // ln_bv
    }
}

// ================= main kernel: 6 barriers, residual fused into final MFMA =================
__global__ __launch_bounds__(NT, 8)
void hydra_kernel(const float* __restrict__ x,
                  const short* __restrict__ wsWd, const short* __restrict__ wsQKVG,
                  const short* __restrict__ wsWu, const float* __restrict__ wsLN,
                  const float* __restrict__ wsW1T, const float* __restrict__ wsW2T,
                  const float* __restrict__ bg,
                  const float* __restrict__ bu,
                  const float* __restrict__ b1, const float* __restrict__ b2,
                  float* __restrict__ out)
{
    __shared__ short hbf[CC * DD];      // 32 KB h tile bf16 swizzled (kept to the end — residual source)
    __shared__ short wreg[RR * DD];     // 16 KB: gWd^T -> qkvg -> Wu^T
    __shared__ short qg[CC * RR];       // 4 KB  Q_n*G bf16 [c][r] linear
    __shared__ short lowbuf[CC * RR];   // 4 KB  hlow -> Abuf (swizzled nswz)
    __shared__ float redA[1024];        // 4 KB  W1 partials [8][64]@0 ; gf [8][32]@512
    __shared__ float redB[2048];        // 8 KB  chanvar -> kv fp32
    __shared__ float redC[1024];        // 4 KB  LN partials (P0->P1): [c][8] float2
    __shared__ float mu_s[CC], rstd_s[CC];
    __shared__ float cv_s[DD], gate_s[DD];
    __shared__ float hid_s[64];
    __shared__ float ln_a[RR], ln_bv[RR];

    const int t    = threadIdx.x;
    const int lane = t & 63;
    const int w    = t >> 6;
    const int bp   = blockIdx.x;
    const int b    = bp / PB;
    const int p    = bp - b * PB;
    const size_t rowbase = (size_t)(b * CC) * PB * DD + (size_t)p * DD;

    // ---- P0: load x -> hbf bf16 swizzled; LN partials (3-stage); copy gWd^T + ln vectors ----
    #pragma unroll
    for (int i = 0; i < 4; ++i) {
        const int c = w * 4 + i;
        const float4 v = *(const float4*)(x + rowbase + (size_t)c * (PB * DD) + 4 * lane);
        float s1 = v.x + v.y + v.z + v.w;
        float s2 = v.x * v.x + v.y * v.y + v.z * v.z + v.w * v.w;
        s1 += __shfl_xor(s1, 1, 64); s2 += __shfl_xor(s2, 1, 64);
        s1 += __shfl_xor(s1, 2, 64); s2 += __shfl_xor(s2, 2, 64);
        s1 += __shfl_xor(s1, 4, 64); s2 += __shfl_xor(s2, 4, 64);
        if ((lane & 7) == 0)
            *(float2*)&redC[(c * 8 + (lane >> 3)) * 2] = make_float2(s1, s2);
        ushort4 pk;
        pk.x = (unsigned short)f2bf(v.x); pk.y = (unsigned short)f2bf(v.y);
        pk.z = (unsigned short)f2bf(v.z); pk.w = (unsigned short)f2bf(v.w);
        *(ushort4*)&hbf[hswz(c, 4 * lane)] = pk;
    }
    *(short8*)&wreg[t * 8] = *(const short8*)&wsWd[t * 8];
    if (t < 32)              ln_a[t]       = wsLN[t];
    else if (t < 64)         ln_bv[t - 32] = wsLN[t];
    __syncthreads();

    // ---- P1: [w0-7] S3 MFMA (h @ gWd)   [w8-15] chan_var partials + LN finalize ----
    f32x4 s3acc = {0.f, 0.f, 0.f, 0.f};
    if (w < 8) {
        const int ct = w >> 1, rt = w & 1;
        const int arow = ct * 16 + (lane & 15);
        const int brow = rt * 16 + (lane & 15);
        const int ksub = lane >> 4;
        #pragma unroll
        for (int step = 0; step < 8; ++step) {
            const short8 a  = *(const short8*)&hbf[hswz(arow, step * 32 + ksub * 8)];
            const short8 bf = *(const short8*)&wreg[hswz(brow, step * 32 + ksub * 8)];
            s3acc = __builtin_amdgcn_mfma_f32_16x16x32_bf16(a, bf, s3acc, 0, 0, 0);
        }
    } else {
        const int idx = t - 512;                 // 0..511
        const int dp  = idx & 127;
        const int rg  = idx >> 7;
        const int d0  = dp * 2;
        float s1a = 0.f, s1b = 0.f, s2a = 0.f, s2b = 0.f;
        #pragma unroll
        for (int i = 0; i < 16; ++i) {
            const int c = rg * 16 + i;
            const ushort2 u = *(const ushort2*)&hbf[hswz(c, d0)];
            const float va = b2f(u.x), vb = b2f(u.y);
            s1a += va; s2a += va * va;
            s1b += vb; s2b += vb * vb;
        }
        *(float2*)&redB[rg * 256 + d0]        = make_float2(s1a, s1b);
        *(float2*)&redB[1024 + rg * 256 + d0] = make_float2(s2a, s2b);
        if (idx < 64) {                          // LN finalize for row c=idx
            const int c = idx;
            float s1 = 0.f, s2 = 0.f;
            #pragma unroll
            for (int g = 0; g < 8; ++g) {
                const float2 pr = *(const float2*)&redC[(c * 8 + g) * 2];
                s1 += pr.x; s2 += pr.y;
            }
            const float mu = s1 * (1.f / 256.f);
            mu_s[c]   = mu;
            rstd_s[c] = rsqrtf(s2 * (1.f / 256.f) - mu * mu + 1e-5f);
        }
    }
    __syncthreads();

    // ---- P2: [w0-7] S3 epilogue -> lowbuf   [w8-15] copy qkvg ; cv finalize ----
    if (w < 8) {
        const int ct = w >> 1, rt = w & 1;
        const int col = rt * 16 + (lane & 15);
        const float la = ln_a[col], lb = ln_bv[col];
        #pragma unroll
        for (int i = 0; i < 4; ++i) {
            const int c = ct * 16 + (lane >> 4) * 4 + i;
            const float rs = rstd_s[c];
            const float hl = rs * s3acc[i] - rs * mu_s[c] * la + lb;
            lowbuf[nswz(c, col)] = f2bf(hl);
        }
    } else {
        const int idx = t - 512;
        *(short8*)&wreg[idx * 8] = *(const short8*)&wsQKVG[idx * 8];
    }
    if (t < 256) {
        const float S1 = redB[t] + redB[256 + t] + redB[512 + t] + redB[768 + t];
        const float S2 = redB[1024 + t] + redB[1280 + t] + redB[1536 + t] + redB[1792 + t];
        cv_s[t] = (S2 - S1 * S1 * (1.f / 64.f)) * (1.f / 63.f);
    }
    __syncthreads();

    // ---- P3: [w0-7] S5 MFMA (QG / KV)   [w8-15] W1 partials (from W1T fp32) ----
    if (w < 8) {
        const int ct = w >> 1, pair = w & 1;
        const int mA = pair ? 1 : 0;   // K or Q (l2-normalized)
        const int mB = pair ? 2 : 3;   // V or G
        const int arow = ct * 16 + (lane & 15);
        const int ksub = lane >> 4;
        const short8 a = *(const short8*)&lowbuf[nswz(arow, ksub * 8)];
        f32x4 aA0 = {0,0,0,0}, aA1 = {0,0,0,0}, aB0 = {0,0,0,0}, aB1 = {0,0,0,0};
        {
            const int br0 = (lane & 15), br1 = 16 + (lane & 15);
            const short8 bA0 = *(const short8*)&wreg[mA * 1024 + nswz(br0, ksub * 8)];
            const short8 bA1 = *(const short8*)&wreg[mA * 1024 + nswz(br1, ksub * 8)];
            const short8 bB0 = *(const short8*)&wreg[mB * 1024 + nswz(br0, ksub * 8)];
            const short8 bB1 = *(const short8*)&wreg[mB * 1024 + nswz(br1, ksub * 8)];
            aA0 = __builtin_amdgcn_mfma_f32_16x16x32_bf16(a, bA0, aA0, 0, 0, 0);
            aA1 = __builtin_amdgcn_mfma_f32_16x16x32_bf16(a, bA1, aA1, 0, 0, 0);
            aB0 = __builtin_amdgcn_mfma_f32_16x16x32_bf16(a, bB0, aB0, 0, 0, 0);
            aB1 = __builtin_amdgcn_mfma_f32_16x16x32_bf16(a, bB1, aB1, 0, 0, 0);
        }
        float qs[4];
        #pragma unroll
        for (int i = 0; i < 4; ++i) {
            float ss = aA0[i] * aA0[i] + aA1[i] * aA1[i];
            ss += __shfl_xor(ss, 1, 64);
            ss += __shfl_xor(ss, 2, 64);
            ss += __shfl_xor(ss, 4, 64);
            ss += __shfl_xor(ss, 8, 64);
            qs[i] = 1.f / fmaxf(sqrtf(ss), 1e-12f);
        }
        const int col0 = (lane & 15), col1 = 16 + (lane & 15);
        if (pair == 0) {
            const float bgv0 = bg[col0], bgv1 = bg[col1];
            #pragma unroll
            for (int i = 0; i < 4; ++i) {
                const int c = ct * 16 + (lane >> 4) * 4 + i;
                const float g0 = 1.f / (1.f + __expf(-(aB0[i] + bgv0)));
                const float g1 = 1.f / (1.f + __expf(-(aB1[i] + bgv1)));
                qg[c * 32 + col0] = f2bf(aA0[i] * qs[i] * g0);
                qg[c * 32 + col1] = f2bf(aA1[i] * qs[i] * g1);
            }
        } else {
            #pragma unroll
            for (int i = 0; i < 4; ++i) {
                const int c = ct * 16 + (lane >> 4) * 4 + i;
                redB[c * 32 + col0] = aA0[i] * qs[i] * aB0[i];   // K_n * V, fp32
                redB[c * 32 + col1] = aA1[i] * qs[i] * aB1[i];
            }
        }
    } else {
        const int idx = t - 512;
        const int j = idx & 63, dg = idx >> 6;   // 8 d-groups of 32
        const float* w1row = wsW1T + j * 256 + dg * 32;
        float s = 0.f;
        #pragma unroll
        for (int ii = 0; ii < 8; ++ii) {
            const float4 wv = *(const float4*)(w1row + ii * 4);
            const float4 cvv = *(const float4*)&cv_s[dg * 32 + ii * 4];
            s += cvv.x * wv.x + cvv.y * wv.y + cvv.z * wv.z + cvv.w * wv.w;
        }
        redA[dg * 64 + j] = s;
    }
    __syncthreads();

    // ---- P4: hid gelu ; gf partials ; copy Wu^T ----
    if (t < 64) {
        float s = b1[t];
        #pragma unroll
        for (int g = 0; g < 8; ++g) s += redA[g * 64 + t];
        hid_s[t] = 0.5f * s * (1.f + erff(s * 0.70710678118654752f));
    }
    if (t >= 256 && t < 512) {
        const int idx = t - 256;
        const int r = idx & 31, g = idx >> 5;
        float s = 0.f;
        #pragma unroll
        for (int i = 0; i < 8; ++i)
            s += redB[(g * 8 + i) * 32 + r];
        redA[512 + g * 32 + r] = s;
    }
    *(short8*)&wreg[t * 8] = *(const short8*)&wsWu[t * 8];
    __syncthreads();

    // ---- P5: Abuf = qg*gf (t<256) ; gate full-dot (256<=t<512) ----
    if (t < 256) {
        const int r = t & 31, c0 = t >> 5, c1 = (t >> 5) + 32;
        float gf = 0.f;
        #pragma unroll
        for (int g = 0; g < 8; ++g) gf += redA[512 + g * 32 + r];
        lowbuf[nswz(c0, r)] = f2bf(b2f((unsigned short)qg[c0 * 32 + r]) * gf);
        lowbuf[nswz(c1, r)] = f2bf(b2f((unsigned short)qg[c1 * 32 + r]) * gf);
    } else if (t < 512) {
        const int d = t - 256;
        const float* w2row = wsW2T + d * 64;
        float s = b2[d];
        #pragma unroll
        for (int ii = 0; ii < 16; ++ii) {
            const float4 wv = *(const float4*)(w2row + ii * 4);
            const float4 hv = *(const float4*)&hid_s[ii * 4];
            s += hv.x * wv.x + hv.y * wv.y + hv.z * wv.z + hv.w * wv.w;
        }
        gate_s[d] = 1.f / (1.f + __expf(-s));
    }
    __syncthreads();

    // ---- P6: S8 MFMA (Abuf @ Wu^T) + fused residual store: out = x_bf16 + gate*(acc+bu) ----
    {
        const int ct = w & 3, dg = w >> 2;
        const int arow = ct * 16 + (lane & 15);
        const int ksub = lane >> 4;
        const short8 a = *(const short8*)&lowbuf[nswz(arow, ksub * 8)];
        #pragma unroll
        for (int j = 0; j < 4; ++j) {
            const int col = (dg * 4 + j) * 16 + (lane & 15);
            const short8 bf = *(const short8*)&wreg[nswz(col, ksub * 8)];
            f32x4 acc = {0.f, 0.f, 0.f, 0.f};
            acc = __builtin_amdgcn_mfma_f32_16x16x32_bf16(a, bf, acc, 0, 0, 0);
            const float gt  = gate_s[col];
            const float buv = bu[col];
            #pragma unroll
            for (int i = 0; i < 4; ++i) {
                const int c = ct * 16 + (lane >> 4) * 4 + i;
                const float xv = b2f((unsigned short)hbf[hswz(c, col)]);
                out[rowbase + (size_t)c * (PB * DD) + col] = xv + gt * (acc[i] + buv);
            }
        }
    }
}

extern "C" void kernel_launch(void* const* d_in, const int* in_sizes, int n_in,
                              void* d_out, int out_size, void* d_ws, size_t ws_size,
                              hipStream_t stream) {
    (void)in_sizes; (void)n_in; (void)out_size; (void)ws_size;
    const float* x    = (const float*)d_in[0];
    const float* ln_g = (const float*)d_in[1];
    const float* ln_b = (const float*)d_in[2];
    const float* Wd   = (const float*)d_in[3];
    const float* bd   = (const float*)d_in[4];
    const float* Wq   = (const float*)d_in[5];
    const float* Wk   = (const float*)d_in[6];
    const float* Wv   = (const float*)d_in[7];
    const float* Wg   = (const float*)d_in[8];
    const float* bg   = (const float*)d_in[9];
    const float* Wu   = (const float*)d_in[10];
    const float* bu   = (const float*)d_in[11];
    const float* W1   = (const float*)d_in[12];
    const float* b1   = (const float*)d_in[13];
    const float* W2   = (const float*)d_in[14];
    const float* b2   = (const float*)d_in[15];
    float* out = (float*)d_out;

    short* wsWd   = (short*)d_ws;                  // 8192 shorts @ 0
    short* wsQKVG = wsWd + 8192;                   // 4096 shorts @ 16384B
    short* wsWu   = wsQKVG + 4096;                 // 8192 shorts @ 24576B
    float* wsLN   = (float*)(wsWd + 20480);        // 64 floats   @ 40960B
    float* wsW1T  = wsLN + 64;                     // 16384 f     @ 41216B
    float* wsW2T  = wsW1T + 16384;                 // 16384 f     @ 106752B

    prep_kernel<<<dim3(1), dim3(1024), 0, stream>>>(
        ln_g, ln_b, Wd, bd, Wq, Wk, Wv, Wg, Wu, W1, W2,
        wsWd, wsQKVG, wsWu, wsLN, wsW1T, wsW2T);
    hydra_kernel<<<dim3(32 * PB), dim3(NT), 0, stream>>>(
        x, wsWd, wsQKVG, wsWu, wsLN, wsW1T, wsW2T, bg, bu, b1, b2, out);
}